// Round 3
// baseline (344.930 us; speedup 1.0000x reference)
//
#include <hip/hip_runtime.h>
#include <stdint.h>
#include <math.h>

typedef unsigned short u16;
typedef __attribute__((ext_vector_type(8))) short short8;
typedef __attribute__((ext_vector_type(8))) u16 ushort8;
typedef __attribute__((ext_vector_type(4))) u16 u16x4;
typedef __attribute__((ext_vector_type(4))) float floatx4;

__device__ __forceinline__ u16 f2bf(float f) {
  union { float f; unsigned u; } c; c.f = f;
  unsigned u = c.u;
  return (u16)((u + 0x7fffu + ((u >> 16) & 1u)) >> 16);
}
__device__ __forceinline__ float bf2f(u16 h) {
  union { unsigned u; float f; } c; c.u = (unsigned)h << 16;
  return c.f;
}

// async global->LDS, 16 bytes per lane; LDS dest must be lane-contiguous.
__device__ __forceinline__ void async16(const u16* g, u16* l) {
  auto* gp = reinterpret_cast<const __attribute__((address_space(1))) uint32_t*>(
      reinterpret_cast<uintptr_t>(g));
  auto* lp = reinterpret_cast<__attribute__((address_space(3))) uint32_t*>(
      reinterpret_cast<uintptr_t>(l));
  __builtin_amdgcn_global_load_lds(gp, lp, 16, 0, 0);
}

// s_waitcnt immediates (gfx9 encoding): vmcnt[3:0] | expcnt<<4 | lgkmcnt<<8
#define WAIT_VM4 0xF74  // vmcnt(4)
#define WAIT_VM0 0xF70  // vmcnt(0)

// ---------------------------------------------------------------------------
// 128x128-tile GEMM — the projection dispatch (3x [8192x1024x1024]).
// C = A * B^T.  A: [M][K] bf16 row-major (lda), B: [N][K] bf16 row-major (ldb).
// 4 waves, double-buffered LDS + vmcnt(4) pipeline, 16B-seg XOR swizzle.
// ~4 blocks/CU (52 VGPR + 64 AGPR) -> occupancy hides the barrier drain.
// vpt: z==2 writes C transposed as [4][1024][2048] (vp^T direct).
// ---------------------------------------------------------------------------
template <int OUT_BF16>
__global__ __launch_bounds__(256) void gemm_bt(
    const u16* __restrict__ A, const u16* __restrict__ B, void* __restrict__ Cv,
    int K, int lda, int ldb, int ldc,
    long long sA, long long sB, long long sC,
    float scale, int vpt, u16* __restrict__ vpC) {
  const int bm = blockIdx.x;
  const int bn = blockIdx.y;
  const int m0 = bm * 128;
  const int n0 = bn * 128;
  A += (size_t)blockIdx.z * sA;
  B += (size_t)blockIdx.z * sB;

  __shared__ u16 As[2][4096];
  __shared__ u16 Bs[2][4096];

  const int tid = threadIdx.x;
  const int lane = tid & 63;
  const int wid = tid >> 6;
  const int wm = (wid & 1) * 64;
  const int wn = (wid >> 1) * 64;
  const int fr = lane & 15;   // m/n within 16x16 frag
  const int fq = lane >> 4;   // logical k-segment

  floatx4 acc[4][4] = {};

  const int kt_end = K >> 5;

  const int rowi = tid >> 2;                 // 0..63
  const int segi = tid & 3;                  // physical 16B seg
  const int sgz = segi ^ ((rowi >> 1) & 3);  // logical seg to fetch
  const u16* gA = A + (size_t)(m0 + rowi) * lda + sgz * 8;
  const u16* gB = B + (size_t)(n0 + rowi) * ldb + sgz * 8;

  // fragment read offsets (swizzled), within one 4096-elem buffer
  int offA[4], offB[4];
#pragma unroll
  for (int i = 0; i < 4; ++i) {
    int ra = wm + i * 16 + fr;
    offA[i] = ra * 32 + (fq ^ ((ra >> 1) & 3)) * 8;
    int rb = wn + i * 16 + fr;
    offB[i] = rb * 32 + (fq ^ ((rb >> 1) & 3)) * 8;
  }

  auto issue = [&](int kt) {
    const int k0 = kt << 5;
    const int odd = kt & 1;
    async16(gA + k0, &As[odd][tid * 8]);
    async16(gA + k0 + (size_t)64 * lda, &As[odd][tid * 8 + 2048]);
    async16(gB + k0, &Bs[odd][tid * 8]);
    async16(gB + k0 + (size_t)64 * ldb, &Bs[odd][tid * 8 + 2048]);
  };

  issue(0);
  for (int kt = 0; kt < kt_end; ++kt) {
    if (kt + 1 < kt_end) {
      issue(kt + 1);
      __builtin_amdgcn_s_waitcnt(WAIT_VM4);  // tile kt's 4 loads retired
    } else {
      __builtin_amdgcn_s_waitcnt(WAIT_VM0);
    }
    asm volatile("s_barrier" ::: "memory");

    const u16* ab = As[kt & 1];
    const u16* bb = Bs[kt & 1];
    short8 av[4], bv[4];
#pragma unroll
    for (int i = 0; i < 4; ++i) av[i] = *(const short8*)(ab + offA[i]);
#pragma unroll
    for (int j = 0; j < 4; ++j) bv[j] = *(const short8*)(bb + offB[j]);

#pragma unroll
    for (int i = 0; i < 4; ++i)
#pragma unroll
      for (int j = 0; j < 4; ++j)
        acc[i][j] = __builtin_amdgcn_mfma_f32_16x16x32_bf16(av[i], bv[j],
                                                            acc[i][j], 0, 0, 0);
    asm volatile("s_barrier" ::: "memory");  // readers done before overwrite
  }

  // Epilogue. C/D layout: col = lane&15 (=fr), row = fq*4 + reg.
  if (vpt && blockIdx.z == 2) {
    // write transposed: vpC[b][n][t], b = m>>11, t = m&2047 (T=2048, H=1024)
#pragma unroll
    for (int i = 0; i < 4; ++i) {
      const int m = m0 + wm + i * 16 + fq * 4;
      const int b = m >> 11, t = m & 2047;
#pragma unroll
      for (int j = 0; j < 4; ++j) {
        const int n = n0 + wn + j * 16 + fr;
        u16x4 o;
#pragma unroll
        for (int r = 0; r < 4; ++r) o[r] = f2bf(acc[i][j][r]);
        *(u16x4*)&vpC[(size_t)b * 2097152 + (size_t)n * 2048 + t] = o;
      }
    }
    return;
  }
  if (OUT_BF16) {
    u16* C = (u16*)Cv + (size_t)blockIdx.z * sC;
#pragma unroll
    for (int i = 0; i < 4; ++i) {
      const int m = m0 + wm + i * 16 + fq * 4;
#pragma unroll
      for (int j = 0; j < 4; ++j) {
        const int n = n0 + wn + j * 16 + fr;
#pragma unroll
        for (int r = 0; r < 4; ++r)
          C[(size_t)(m + r) * ldc + n] = f2bf(acc[i][j][r] * scale);
      }
    }
  } else {
    float* C = (float*)Cv + (size_t)blockIdx.z * sC;
#pragma unroll
    for (int i = 0; i < 4; ++i) {
      const int m = m0 + wm + i * 16 + fq * 4;
#pragma unroll
      for (int j = 0; j < 4; ++j) {
        const int n = n0 + wn + j * 16 + fr;
#pragma unroll
        for (int r = 0; r < 4; ++r)
          C[(size_t)(m + r) * ldc + n] = acc[i][j][r] * scale;
      }
    }
  }
}

// ---------------------------------------------------------------------------
// 256x256-tile, 4-phase-per-K-tile pipelined GEMM for the attention GEMMs
// (S = qp*kp^T and out = P*vp^T).  These are HBM-refetch-bound at 128^2:
// 256^2 halves panel traffic, and both grids (144 / 128 working blocks) fit
// in one residency round (1 block/CU), so the tail that killed the 256^2
// projection doesn't apply.
//
// MODE 0 (S): tri grid via XCD-slot decode: bx = s*8 + r; bm=r, bn=s,
//   early-exit if s>r.  Blocks sharing the qp panel (same bm) land on the
//   same XCD (wgid%8 heuristic) -> panel served from that XCD's L2.
//   bf16 out with scale.
// MODE 1 (out): bx = s*8 + r; bm=r (T/256=8), bn=s (H/256=4); causal K
//   limit: NT=(m0+256)/64.  Same-XCD grouping for the P panel. f32 out.
//
// Body = round-1 schedule (the better of the two measured):
//   ph1: ds a(lo)+b0 | stage A0(t+1) | MFMA Q00
//   ph2: ds b1       | stage A1(t+1) | MFMA Q01
//   ph3: ds a(hi)    | stage B0(t+2) | MFMA Q10
//   ph4:             | stage B1(t+2) | MFMA Q11 | vmcnt(4)
// Steady-state in flight: B(t), A(t), B(t+1) -> 12; vmcnt(4) retires
// B(t)+A(t) -> tile t+1 fully resident at next-group entry.
// ---------------------------------------------------------------------------
template <int MODE>
__global__ __launch_bounds__(512, 2) void gemm256(
    const u16* __restrict__ A, const u16* __restrict__ B, void* __restrict__ Cv,
    int K, int lda, int ldb, int ldc,
    long long sA, long long sB, long long sC, float scale) {
  const int r = blockIdx.x & 7;
  const int s = blockIdx.x >> 3;
  if (MODE == 0 && s > r) return;  // upper-triangle slot: idle
  const int bm = r;
  const int bn = s;
  const int m0 = bm * 256;
  const int n0 = bn * 256;
  A += (size_t)blockIdx.z * sA;
  B += (size_t)blockIdx.z * sB;

  __shared__ u16 lds[2][32768];  // [parity][A:16384 | B:16384]

  const int tid = threadIdx.x;  // 0..511
  const int lane = tid & 63;
  const int wid = tid >> 6;     // 0..7
  const int wr = wid & 1;       // row half of the 256-row tile
  const int wc = wid >> 1;      // 0..3 col quarter
  const int fr = lane & 15;
  const int fq = lane >> 4;

  floatx4 acc[8][4] = {};
  const int NT = (MODE == 1) ? ((m0 + 256) >> 6) : (K >> 6);  // K-tiles of 64

  // staging: thread -> (row tid>>3 within 64-row round, phys 16B seg tid&7);
  // fetch the logical seg (tid&7)^(row&7) so the linear LDS image is swizzled.
  const int srow = tid >> 3;
  const int sseg = (tid & 7) ^ (srow & 7);
  const u16* gA = A + (size_t)(m0 + srow) * lda + sseg * 8;
  const u16* gB = B + (size_t)(n0 + srow) * ldb + sseg * 8;
  const int ldst = tid * 8;

  auto stageA = [&](int h, int t) {
    u16* d = &lds[t & 1][h * 8192 + ldst];
    const u16* src = gA + (size_t)(h * 128) * lda + t * 64;
    async16(src, d);
    async16(src + (size_t)64 * lda, d + 4096);
  };
  auto stageB = [&](int h, int t) {
    u16* d = &lds[t & 1][16384 + h * 8192 + ldst];
    const u16* src = gB + (size_t)(h * 128) * ldb + t * 64;
    async16(src, d);
    async16(src + (size_t)64 * ldb, d + 4096);
  };

  // fragment read offsets (elems): row fr of frag, k-seg (sg*4+fq), swizzled
  int aoff[2], boff[2];
#pragma unroll
  for (int sg = 0; sg < 2; ++sg) {
    const int seg = ((((sg << 2) + fq) ^ (fr & 7))) * 8;
    aoff[sg] = wr * 8192 + fr * 64 + seg;
    boff[sg] = 16384 + (wc >> 1) * 8192 + (wc & 1) * 4096 + fr * 64 + seg;
  }

  // prologue: tile0 fully, B halves of tile1 (12 loads); vmcnt(4) -> tile0
  // landed, B(1) in flight — the steady-state group-entry invariant.
  stageA(0, 0); stageA(1, 0); stageB(0, 0); stageB(1, 0);
  stageB(0, 1); stageB(1, 1);
  __builtin_amdgcn_s_waitcnt(WAIT_VM4);
  asm volatile("s_barrier" ::: "memory");

  short8 a[4][2], b0[2][2], b1[2][2];
  for (int t = 0; t < NT; ++t) {
    const u16* L = lds[t & 1];

    // ---- phase 1: quadrant (rows 0-63, cols 0-31) ----
#pragma unroll
    for (int i = 0; i < 4; ++i)
#pragma unroll
      for (int sg = 0; sg < 2; ++sg)
        a[i][sg] = *(const short8*)(L + aoff[sg] + i * 1024);
#pragma unroll
    for (int j = 0; j < 2; ++j)
#pragma unroll
      for (int sg = 0; sg < 2; ++sg)
        b0[j][sg] = *(const short8*)(L + boff[sg] + j * 1024);
    if (t + 1 < NT) stageA(0, t + 1);
    asm volatile("s_barrier" ::: "memory");
    __builtin_amdgcn_s_setprio(1);
#pragma unroll
    for (int i = 0; i < 4; ++i)
#pragma unroll
      for (int j = 0; j < 2; ++j) {
        acc[i][j] = __builtin_amdgcn_mfma_f32_16x16x32_bf16(
            a[i][0], b0[j][0], acc[i][j], 0, 0, 0);
        acc[i][j] = __builtin_amdgcn_mfma_f32_16x16x32_bf16(
            a[i][1], b0[j][1], acc[i][j], 0, 0, 0);
      }
    __builtin_amdgcn_s_setprio(0);
    asm volatile("s_barrier" ::: "memory");

    // ---- phase 2: (rows 0-63, cols 32-63) ----
#pragma unroll
    for (int j = 0; j < 2; ++j)
#pragma unroll
      for (int sg = 0; sg < 2; ++sg)
        b1[j][sg] = *(const short8*)(L + boff[sg] + (2 + j) * 1024);
    if (t + 1 < NT) stageA(1, t + 1);
    asm volatile("s_barrier" ::: "memory");
    __builtin_amdgcn_s_setprio(1);
#pragma unroll
    for (int i = 0; i < 4; ++i)
#pragma unroll
      for (int j = 0; j < 2; ++j) {
        acc[i][2 + j] = __builtin_amdgcn_mfma_f32_16x16x32_bf16(
            a[i][0], b1[j][0], acc[i][2 + j], 0, 0, 0);
        acc[i][2 + j] = __builtin_amdgcn_mfma_f32_16x16x32_bf16(
            a[i][1], b1[j][1], acc[i][2 + j], 0, 0, 0);
      }
    __builtin_amdgcn_s_setprio(0);
    asm volatile("s_barrier" ::: "memory");

    // ---- phase 3: (rows 64-127, cols 0-31); stage B0(t+2) ----
#pragma unroll
    for (int i = 0; i < 4; ++i)
#pragma unroll
      for (int sg = 0; sg < 2; ++sg)
        a[i][sg] = *(const short8*)(L + aoff[sg] + (4 + i) * 1024);
    if (t + 2 < NT) stageB(0, t + 2);
    asm volatile("s_barrier" ::: "memory");
    __builtin_amdgcn_s_setprio(1);
#pragma unroll
    for (int i = 0; i < 4; ++i)
#pragma unroll
      for (int j = 0; j < 2; ++j) {
        acc[4 + i][j] = __builtin_amdgcn_mfma_f32_16x16x32_bf16(
            a[i][0], b0[j][0], acc[4 + i][j], 0, 0, 0);
        acc[4 + i][j] = __builtin_amdgcn_mfma_f32_16x16x32_bf16(
            a[i][1], b0[j][1], acc[4 + i][j], 0, 0, 0);
      }
    __builtin_amdgcn_s_setprio(0);
    asm volatile("s_barrier" ::: "memory");

    // ---- phase 4: (rows 64-127, cols 32-63); stage B1(t+2), group wait ----
    if (t + 2 < NT) {
      stageB(1, t + 2);
      __builtin_amdgcn_s_waitcnt(WAIT_VM4);  // retires B(t)+A(t) leftovers
    } else {
      __builtin_amdgcn_s_waitcnt(WAIT_VM0);  // tail drain
    }
    asm volatile("s_barrier" ::: "memory");
    __builtin_amdgcn_s_setprio(1);
#pragma unroll
    for (int i = 0; i < 4; ++i)
#pragma unroll
      for (int j = 0; j < 2; ++j) {
        acc[4 + i][2 + j] = __builtin_amdgcn_mfma_f32_16x16x32_bf16(
            a[i][0], b1[j][0], acc[4 + i][2 + j], 0, 0, 0);
        acc[4 + i][2 + j] = __builtin_amdgcn_mfma_f32_16x16x32_bf16(
            a[i][1], b1[j][1], acc[4 + i][2 + j], 0, 0, 0);
      }
    __builtin_amdgcn_s_setprio(0);
    asm volatile("s_barrier" ::: "memory");
  }

  // epilogue. C/D frag layout: col = fr, row = fq*4 + reg.
  const int mBase = m0 + wr * 128;
  const int nBase = n0 + wc * 64;
  if (MODE == 0) {
    u16* Co = (u16*)Cv + (size_t)blockIdx.z * sC;
#pragma unroll
    for (int i = 0; i < 8; ++i) {
      const int m = mBase + i * 16 + fq * 4;
#pragma unroll
      for (int j = 0; j < 4; ++j) {
        const int n = nBase + j * 16 + fr;
#pragma unroll
        for (int rg = 0; rg < 4; ++rg)
          Co[(size_t)(m + rg) * ldc + n] = f2bf(acc[i][j][rg] * scale);
      }
    }
  } else {
    float* Co = (float*)Cv + (size_t)blockIdx.z * sC;
#pragma unroll
    for (int i = 0; i < 8; ++i) {
      const int m = mBase + i * 16 + fq * 4;
#pragma unroll
      for (int j = 0; j < 4; ++j) {
        const int n = nBase + j * 16 + fr;
#pragma unroll
        for (int rg = 0; rg < 4; ++rg)
          Co[(size_t)(m + rg) * ldc + n] = acc[i][j][rg] * scale;
      }
    }
  }
}

// fp32 -> bf16 cast for q,k,v in one dispatch (blockIdx.y selects source)
__global__ __launch_bounds__(256) void cast3(
    const float* __restrict__ q, const float* __restrict__ k,
    const float* __restrict__ v, u16* __restrict__ out, int n8) {
  int i = blockIdx.x * 256 + threadIdx.x;
  if (i >= n8) return;
  const float* src = blockIdx.y == 0 ? q : (blockIdx.y == 1 ? k : v);
  u16* dst = out + (size_t)blockIdx.y * n8 * 8;
  floatx4 a = ((const floatx4*)src)[i * 2];
  floatx4 b = ((const floatx4*)src)[i * 2 + 1];
  ushort8 o;
#pragma unroll
  for (int j = 0; j < 4; ++j) { o[j] = f2bf(a[j]); o[4 + j] = f2bf(b[j]); }
  ((ushort8*)dst)[i] = o;
}

// fp32 [R][C] -> bf16 [C][R] transpose+cast, 64x64 tiles; z picks (Wq,Wk,Wq)
__global__ __launch_bounds__(256) void transpose_castW(
    const float* __restrict__ Wq, const float* __restrict__ Wk,
    u16* __restrict__ out, int R, int C) {
  __shared__ u16 tile[64][72];
  const float* in = (blockIdx.z == 1) ? Wk : Wq;
  u16* dst = out + (size_t)blockIdx.z * R * C;
  const int r0 = blockIdx.x * 64;
  const int c0 = blockIdx.y * 64;
  const int tid = threadIdx.x;
#pragma unroll
  for (int rnd = 0; rnd < 2; ++rnd) {
    int e = rnd * 256 + tid;
    int rr = e >> 3, seg = e & 7;
    const float* p = &in[(size_t)(r0 + rr) * C + c0 + seg * 8];
    floatx4 a = *(const floatx4*)p;
    floatx4 b = *(const floatx4*)(p + 4);
    u16* tp = &tile[rr][seg * 8];
#pragma unroll
    for (int j = 0; j < 4; ++j) { tp[j] = f2bf(a[j]); tp[4 + j] = f2bf(b[j]); }
  }
  __syncthreads();
#pragma unroll
  for (int rnd = 0; rnd < 2; ++rnd) {
    int e = rnd * 256 + tid;
    int cc = e >> 3, rseg = e & 7;
    ushort8 tv;
#pragma unroll
    for (int j = 0; j < 8; ++j) tv[j] = tile[rseg * 8 + j][cc];
    *(ushort8*)&dst[(size_t)(c0 + cc) * R + r0 + rseg * 8] = tv;
  }
}

// Causal row softmax, bf16 in-place. All reads complete before the sum-barrier;
// writes only after it -> in-place safe within the block's own row.
// Zero-fill only to the next 256 boundary: the 256^2 out-gemm's causal K
// limit (m0+256) never reads past it.
__global__ __launch_bounds__(256) void softmax_causal(u16* __restrict__ S,
                                                      int T) {
  const int row = blockIdx.x;
  const int t = row & (T - 1);
  const int len = t + 1;
  u16* srow = S + (size_t)row * T;
  const int tid = threadIdx.x;

  float vals[8];
  int cnt = 0;
  float mx = -1e30f;
  for (int i = tid; i < len; i += 256) {
    float v = bf2f(srow[i]);
    vals[cnt++] = v;
    mx = fmaxf(mx, v);
  }
  __shared__ float red[4];
#pragma unroll
  for (int o = 32; o > 0; o >>= 1) mx = fmaxf(mx, __shfl_down(mx, o, 64));
  if ((tid & 63) == 0) red[tid >> 6] = mx;
  __syncthreads();
  mx = fmaxf(fmaxf(red[0], red[1]), fmaxf(red[2], red[3]));
  __syncthreads();

  float sum = 0.f;
  for (int c = 0; c < cnt; ++c) {
    vals[c] = __expf(vals[c] - mx);
    sum += vals[c];
  }
#pragma unroll
  for (int o = 32; o > 0; o >>= 1) sum += __shfl_down(sum, o, 64);
  if ((tid & 63) == 0) red[tid >> 6] = sum;
  __syncthreads();
  sum = red[0] + red[1] + red[2] + red[3];
  const float inv = 1.f / sum;

  int c = 0;
  for (int i = tid; i < len; i += 256) srow[i] = f2bf(vals[c++] * inv);
  const int zlim = ((t >> 8) + 1) << 8;  // next 256 boundary (<= T)
  for (int i = tid; i < zlim; i += 256)
    if (i >= len) srow[i] = 0;
}

extern "C" void kernel_launch(void* const* d_in, const int* in_sizes, int n_in,
                              void* d_out, int out_size, void* d_ws,
                              size_t ws_size, hipStream_t stream) {
  (void)in_sizes; (void)n_in; (void)out_size; (void)ws_size;
  const float* k  = (const float*)d_in[1];
  const float* q  = (const float*)d_in[2];
  const float* v  = (const float*)d_in[3];
  const float* Wk = (const float*)d_in[4];
  const float* Wq = (const float*)d_in[5];
  float* out = (float*)d_out;

  const int B = 4, T = 2048, C = 1024, H = 1024;
  const int M = B * T;  // 8192
  const size_t MC = (size_t)M * C, CH = (size_t)C * H, MH = (size_t)M * H;

  u16* qkv  = (u16*)d_ws;        // 3 slots [M][C] bf16 (q,k,v)        50 MB
  u16* WT   = qkv + 3 * MC;      // 3 slots [H][C] bf16 (Wq,Wk,Wq)      6 MB
  u16* qkvp = WT + 3 * CH;       // slot0 qp, slot1 kp [M][H]          34 MB
  u16* vpT  = qkvp + 2 * MH;     // [B][H][T] bf16 (vp^T, direct)      17 MB
  u16* Sb   = vpT + MH;          // [B][T][T] bf16 (S, then P)       33.5 MB

  const int n8 = (int)(MC / 8);
  cast3<<<dim3(n8 / 256, 3), 256, 0, stream>>>(q, k, v, qkv, n8);
  transpose_castW<<<dim3(C / 64, H / 64, 3), 256, 0, stream>>>(Wq, Wk, WT, C, H);

  // qp = q*Wq, kp = k*Wk, vp^T = (v*Wq)^T — 128^2 kernel (best measured)
  gemm_bt<1><<<dim3(M / 128, H / 128, 3), 256, 0, stream>>>(
      qkv, WT, qkvp, C, C, C, H,
      (long long)MC, (long long)CH, (long long)MH, 1.f, 1, vpT);

  // S = qp*kp^T / 32 (bf16), 256^2 tri tiles; XCD-slot grid 8x8 (36 live)
  gemm256<0><<<dim3(64, 1, B), 512, 0, stream>>>(
      qkvp, qkvp + MH, Sb, H, H, H, T,
      (long long)T * H, (long long)T * H, (long long)T * T, 0.03125f);

  softmax_causal<<<dim3(B * T), 256, 0, stream>>>(Sb, T);

  // out = P * vpT^T (K limited to m0+256), 256^2 tiles; grid 8x4 per batch
  gemm256<1><<<dim3(32, 1, B), 512, 0, stream>>>(
      Sb, vpT, out, T, T, T, H,
      (long long)T * T, (long long)H * T, (long long)T * H, 1.f);
}

// Round 4
// 318.506 us; speedup vs baseline: 1.0830x; 1.0830x over previous
//
#include <hip/hip_runtime.h>
#include <stdint.h>
#include <math.h>

typedef unsigned short u16;
typedef __attribute__((ext_vector_type(8))) short short8;
typedef __attribute__((ext_vector_type(8))) u16 ushort8;
typedef __attribute__((ext_vector_type(4))) u16 u16x4;
typedef __attribute__((ext_vector_type(4))) float floatx4;

__device__ __forceinline__ u16 f2bf(float f) {
  union { float f; unsigned u; } c; c.f = f;
  unsigned u = c.u;
  return (u16)((u + 0x7fffu + ((u >> 16) & 1u)) >> 16);
}
__device__ __forceinline__ float bf2f(u16 h) {
  union { unsigned u; float f; } c; c.u = (unsigned)h << 16;
  return c.f;
}

// async global->LDS, 16 bytes per lane; LDS dest must be lane-contiguous.
__device__ __forceinline__ void async16(const u16* g, u16* l) {
  auto* gp = reinterpret_cast<const __attribute__((address_space(1))) uint32_t*>(
      reinterpret_cast<uintptr_t>(g));
  auto* lp = reinterpret_cast<__attribute__((address_space(3))) uint32_t*>(
      reinterpret_cast<uintptr_t>(l));
  __builtin_amdgcn_global_load_lds(gp, lp, 16, 0, 0);
}

// s_waitcnt immediates (gfx9 encoding): vmcnt[3:0] | expcnt<<4 | lgkmcnt<<8
#define WAIT_VM4 0xF74  // vmcnt(4): wait until <=4 vmem ops outstanding
#define WAIT_VM0 0xF70  // vmcnt(0)

// ---------------------------------------------------------------------------
// C = A * B^T.  A: [M][K] bf16 row-major (lda), B: [N][K] bf16 row-major (ldb).
// 256 threads = 4 waves, 128x128 tile, per-wave 64x64.  ~4 blocks/CU
// (52 VGPR + 64 AGPR, 32 KB LDS) -> occupancy hides the barrier drain.
// Double-buffered LDS + vmcnt(4) pipeline (loads stay in flight across the
// barrier).  LDS XOR swizzle: 16B seg s of row r at phys seg s^((r>>1)&3).
// tri_grid: blockIdx.x enumerates lower-triangle tiles (S gemm).
// rev_m: reverse m-tile order so heavy causal_klimit blocks launch first.
// vpt: z==2 writes C transposed as [4][1024][2048] (vp^T direct).
// ---------------------------------------------------------------------------
template <int OUT_BF16>
__global__ __launch_bounds__(256) void gemm_bt(
    const u16* __restrict__ A, const u16* __restrict__ B, void* __restrict__ Cv,
    int K, int lda, int ldb, int ldc,
    long long sA, long long sB, long long sC,
    float scale, int tri_grid, int causal_klimit, int rev_m,
    int vpt, u16* __restrict__ vpC) {
  int bm, bn;
  if (tri_grid) {
    const int bx = blockIdx.x;
    int i = (int)((sqrtf(8.f * bx + 1.f) - 1.f) * 0.5f);
    while ((i + 1) * (i + 2) / 2 <= bx) ++i;
    while (i * (i + 1) / 2 > bx) --i;
    bm = i;
    bn = bx - i * (i + 1) / 2;
  } else {
    bm = rev_m ? ((int)gridDim.x - 1 - (int)blockIdx.x) : (int)blockIdx.x;
    bn = blockIdx.y;
  }
  const int m0 = bm * 128;
  const int n0 = bn * 128;
  A += (size_t)blockIdx.z * sA;
  B += (size_t)blockIdx.z * sB;

  __shared__ u16 As[2][4096];
  __shared__ u16 Bs[2][4096];

  const int tid = threadIdx.x;
  const int lane = tid & 63;
  const int wid = tid >> 6;
  const int wm = (wid & 1) * 64;
  const int wn = (wid >> 1) * 64;
  const int fr = lane & 15;   // m/n within 16x16 frag
  const int fq = lane >> 4;   // logical k-segment

  floatx4 acc[4][4] = {};

  int kt_end = K >> 5;
  if (causal_klimit) {
    int lim = (m0 >> 5) + 4;
    if (lim < kt_end) kt_end = lim;
  }

  const int rowi = tid >> 2;                 // 0..63
  const int segi = tid & 3;                  // physical 16B seg
  const int sgz = segi ^ ((rowi >> 1) & 3);  // logical seg to fetch
  const u16* gA = A + (size_t)(m0 + rowi) * lda + sgz * 8;
  const u16* gB = B + (size_t)(n0 + rowi) * ldb + sgz * 8;

  // fragment read offsets (swizzled), within one 4096-elem buffer
  int offA[4], offB[4];
#pragma unroll
  for (int i = 0; i < 4; ++i) {
    int ra = wm + i * 16 + fr;
    offA[i] = ra * 32 + (fq ^ ((ra >> 1) & 3)) * 8;
    int rb = wn + i * 16 + fr;
    offB[i] = rb * 32 + (fq ^ ((rb >> 1) & 3)) * 8;
  }

  auto issue = [&](int kt) {
    const int k0 = kt << 5;
    const int odd = kt & 1;
    async16(gA + k0, &As[odd][tid * 8]);
    async16(gA + k0 + (size_t)64 * lda, &As[odd][tid * 8 + 2048]);
    async16(gB + k0, &Bs[odd][tid * 8]);
    async16(gB + k0 + (size_t)64 * ldb, &Bs[odd][tid * 8 + 2048]);
  };

  issue(0);
  for (int kt = 0; kt < kt_end; ++kt) {
    if (kt + 1 < kt_end) {
      issue(kt + 1);
      __builtin_amdgcn_s_waitcnt(WAIT_VM4);  // tile kt's 4 loads retired
    } else {
      __builtin_amdgcn_s_waitcnt(WAIT_VM0);
    }
    asm volatile("s_barrier" ::: "memory");

    const u16* ab = As[kt & 1];
    const u16* bb = Bs[kt & 1];
    short8 av[4], bv[4];
#pragma unroll
    for (int i = 0; i < 4; ++i) av[i] = *(const short8*)(ab + offA[i]);
#pragma unroll
    for (int j = 0; j < 4; ++j) bv[j] = *(const short8*)(bb + offB[j]);

#pragma unroll
    for (int i = 0; i < 4; ++i)
#pragma unroll
      for (int j = 0; j < 4; ++j)
        acc[i][j] = __builtin_amdgcn_mfma_f32_16x16x32_bf16(av[i], bv[j],
                                                            acc[i][j], 0, 0, 0);
    asm volatile("s_barrier" ::: "memory");  // readers done before overwrite
  }

  // Epilogue. C/D layout: col = lane&15 (=fr), row = fq*4 + reg.
  if (vpt && blockIdx.z == 2) {
    // write transposed: vpC[b][n][t], b = m>>11, t = m&2047 (T=2048, H=1024)
#pragma unroll
    for (int i = 0; i < 4; ++i) {
      const int m = m0 + wm + i * 16 + fq * 4;
      const int b = m >> 11, t = m & 2047;
#pragma unroll
      for (int j = 0; j < 4; ++j) {
        const int n = n0 + wn + j * 16 + fr;
        u16x4 o;
#pragma unroll
        for (int r = 0; r < 4; ++r) o[r] = f2bf(acc[i][j][r]);
        *(u16x4*)&vpC[(size_t)b * 2097152 + (size_t)n * 2048 + t] = o;
      }
    }
    return;
  }
  if (OUT_BF16) {
    u16* C = (u16*)Cv + (size_t)blockIdx.z * sC;
#pragma unroll
    for (int i = 0; i < 4; ++i) {
      const int m = m0 + wm + i * 16 + fq * 4;
#pragma unroll
      for (int j = 0; j < 4; ++j) {
        const int n = n0 + wn + j * 16 + fr;
#pragma unroll
        for (int r = 0; r < 4; ++r)
          C[(size_t)(m + r) * ldc + n] = f2bf(acc[i][j][r] * scale);
      }
    }
  } else {
    float* C = (float*)Cv + (size_t)blockIdx.z * sC;
#pragma unroll
    for (int i = 0; i < 4; ++i) {
      const int m = m0 + wm + i * 16 + fq * 4;
#pragma unroll
      for (int j = 0; j < 4; ++j) {
        const int n = n0 + wn + j * 16 + fr;
#pragma unroll
        for (int r = 0; r < 4; ++r)
          C[(size_t)(m + r) * ldc + n] = acc[i][j][r] * scale;
      }
    }
  }
}

// fp32 -> bf16 cast for q,k,v in one dispatch (blockIdx.y selects source)
__global__ __launch_bounds__(256) void cast3(
    const float* __restrict__ q, const float* __restrict__ k,
    const float* __restrict__ v, u16* __restrict__ out, int n8) {
  int i = blockIdx.x * 256 + threadIdx.x;
  if (i >= n8) return;
  const float* src = blockIdx.y == 0 ? q : (blockIdx.y == 1 ? k : v);
  u16* dst = out + (size_t)blockIdx.y * n8 * 8;
  floatx4 a = ((const floatx4*)src)[i * 2];
  floatx4 b = ((const floatx4*)src)[i * 2 + 1];
  ushort8 o;
#pragma unroll
  for (int j = 0; j < 4; ++j) { o[j] = f2bf(a[j]); o[4 + j] = f2bf(b[j]); }
  ((ushort8*)dst)[i] = o;
}

// fp32 [R][C] -> bf16 [C][R] transpose+cast, 64x64 tiles; z picks (Wq,Wk,Wq)
__global__ __launch_bounds__(256) void transpose_castW(
    const float* __restrict__ Wq, const float* __restrict__ Wk,
    u16* __restrict__ out, int R, int C) {
  __shared__ u16 tile[64][72];
  const float* in = (blockIdx.z == 1) ? Wk : Wq;
  u16* dst = out + (size_t)blockIdx.z * R * C;
  const int r0 = blockIdx.x * 64;
  const int c0 = blockIdx.y * 64;
  const int tid = threadIdx.x;
#pragma unroll
  for (int rnd = 0; rnd < 2; ++rnd) {
    int e = rnd * 256 + tid;
    int rr = e >> 3, seg = e & 7;
    const float* p = &in[(size_t)(r0 + rr) * C + c0 + seg * 8];
    floatx4 a = *(const floatx4*)p;
    floatx4 b = *(const floatx4*)(p + 4);
    u16* tp = &tile[rr][seg * 8];
#pragma unroll
    for (int j = 0; j < 4; ++j) { tp[j] = f2bf(a[j]); tp[4 + j] = f2bf(b[j]); }
  }
  __syncthreads();
#pragma unroll
  for (int rnd = 0; rnd < 2; ++rnd) {
    int e = rnd * 256 + tid;
    int cc = e >> 3, rseg = e & 7;
    ushort8 tv;
#pragma unroll
    for (int j = 0; j < 8; ++j) tv[j] = tile[rseg * 8 + j][cc];
    *(ushort8*)&dst[(size_t)(c0 + cc) * R + r0 + rseg * 8] = tv;
  }
}

// Causal row softmax, bf16 in-place, single pass.  T must be 2048:
// 256 threads x ushort8 = one 16B vector load + one store per thread.
// NO runtime-indexed locals (rule #20: they'd spill to scratch) — all
// per-thread state is statically indexed; causal mask via per-element
// select to -1e30 (exp -> 0), which also zero-fills the upper triangle.
// In-place safe: all reads precede the first barrier; writes follow the last.
__global__ __launch_bounds__(256) void softmax_causal(u16* __restrict__ S,
                                                      int T) {
  const int row = blockIdx.x;
  const int t = row & (T - 1);
  const int len = t + 1;
  u16* srow = S + (size_t)row * T;
  const int tid = threadIdx.x;
  const int base = tid * 8;

  const ushort8 raw = *(const ushort8*)(srow + base);
  float v[8];
  float mx = -1e30f;
#pragma unroll
  for (int j = 0; j < 8; ++j) {
    const float f = bf2f(raw[j]);
    v[j] = (base + j < len) ? f : -1e30f;
    mx = fmaxf(mx, v[j]);
  }
#pragma unroll
  for (int o = 32; o > 0; o >>= 1) mx = fmaxf(mx, __shfl_xor(mx, o, 64));

  __shared__ float red[8];
  if ((tid & 63) == 0) red[tid >> 6] = mx;
  __syncthreads();
  mx = fmaxf(fmaxf(red[0], red[1]), fmaxf(red[2], red[3]));

  float sum = 0.f;
#pragma unroll
  for (int j = 0; j < 8; ++j) {
    const float e = __expf(v[j] - mx);  // masked lanes: exp(-huge) = 0
    v[j] = e;
    sum += e;
  }
#pragma unroll
  for (int o = 32; o > 0; o >>= 1) sum += __shfl_xor(sum, o, 64);
  if ((tid & 63) == 0) red[4 + (tid >> 6)] = sum;
  __syncthreads();
  sum = red[4] + red[5] + red[6] + red[7];
  const float inv = 1.f / sum;

  ushort8 o8;
#pragma unroll
  for (int j = 0; j < 8; ++j) o8[j] = f2bf(v[j] * inv);
  *(ushort8*)(srow + base) = o8;
}

extern "C" void kernel_launch(void* const* d_in, const int* in_sizes, int n_in,
                              void* d_out, int out_size, void* d_ws,
                              size_t ws_size, hipStream_t stream) {
  (void)in_sizes; (void)n_in; (void)out_size; (void)ws_size;
  const float* k  = (const float*)d_in[1];
  const float* q  = (const float*)d_in[2];
  const float* v  = (const float*)d_in[3];
  const float* Wk = (const float*)d_in[4];
  const float* Wq = (const float*)d_in[5];
  float* out = (float*)d_out;

  const int B = 4, T = 2048, C = 1024, H = 1024;
  const int M = B * T;  // 8192
  const size_t MC = (size_t)M * C, CH = (size_t)C * H, MH = (size_t)M * H;

  u16* qkv  = (u16*)d_ws;        // 3 slots [M][C] bf16 (q,k,v)        50 MB
  u16* WT   = qkv + 3 * MC;      // 3 slots [H][C] bf16 (Wq,Wk,Wq)      6 MB
  u16* qkvp = WT + 3 * CH;       // slot0 qp, slot1 kp [M][H]          34 MB
  u16* vpT  = qkvp + 2 * MH;     // [B][H][T] bf16 (vp^T, direct)      17 MB
  u16* Sb   = vpT + MH;          // [B][T][T] bf16 (S, then P)       33.5 MB

  const int n8 = (int)(MC / 8);
  cast3<<<dim3(n8 / 256, 3), 256, 0, stream>>>(q, k, v, qkv, n8);
  transpose_castW<<<dim3(C / 64, H / 64, 3), 256, 0, stream>>>(Wq, Wk, WT, C, H);

  // qp = q*Wq, kp = k*Wk, vp^T = (v*Wq)^T  (one batched dispatch, z=0..2)
  gemm_bt<1><<<dim3(M / 128, H / 128, 3), 256, 0, stream>>>(
      qkv, WT, qkvp, C, C, C, H,
      (long long)MC, (long long)CH, (long long)MH, 1.f, 0, 0, 0, 1, vpT);

  // S = qp*kp^T / 32 (bf16 out), compact lower-triangle grid (136 tiles/batch)
  gemm_bt<1><<<dim3(136, 1, B), 256, 0, stream>>>(
      qkvp, qkvp + MH, Sb, H, H, H, T,
      (long long)T * H, (long long)T * H, (long long)T * T,
      0.03125f, 1, 0, 0, 0, nullptr);

  softmax_causal<<<dim3(B * T), 256, 0, stream>>>(Sb, T);

  // out = P * vpT^T (K limited to m0+128: P zero above diagonal), heavy-first
  gemm_bt<0><<<dim3(T / 128, H / 128, B), 256, 0, stream>>>(
      Sb, vpT, out, T, T, T, H,
      (long long)T * T, (long long)H * T, (long long)T * H,
      1.f, 0, 1, 1, 0, nullptr);
}